// Round 10
// baseline (74.889 us; speedup 1.0000x reference)
//
#include <hip/hip_runtime.h>
#include <math.h>

// FeatureLabelLoss: features (B,C,D) f32, embeddings (C,D) f32, labels (B,C) f32
// -> scalar f32 loss.  BW-bound on the 327.7 MB features stream.
//
// Lessons:
//  R2: NO per-block __threadfence (buffer_wbl2 serializes the chip).
//  R5: NO same-LINE atomic hammering (5000 serialized fp64 adds = +79 us);
//      but the fence-free ordering pattern (atomic -> vmcnt(0) -> counter)
//      itself is correctness-proven (absmax 0.0).
//  R6: tail/balance is NOT the limiter. R7: contiguity+LDS = worse (DS traffic).
//  R8: DPP (VALU-only) wave reduction: -1.4 us; hot loop has zero DS ops.
//      Main dispatch ~59-60 us = ~92% of copy-ceiling BW; finish ~4-6 us.
//
// R9 single change vs R8: fused finish. Per-block f64 atomicAdd into one of
// 16 LINE-STRIDED buckets (80 adds/line, spread over the completion tail),
// two-level arrival counters (16 line-strided + 1 master), last block sums
// the 16 buckets via independent atomic reads. No 2nd kernel, no fences.

typedef float f32x4 __attribute__((ext_vector_type(4)));

constexpr int B = 32;
constexpr int C = 5000;
constexpr int D = 512;                 // 512 floats = 2 f32x4 per lane
constexpr int NROWS = B * C;           // 160000
constexpr float EPS_LOG = 1e-6f;

constexpr int WPB = 4;                 // waves per block
constexpr int THREADS = WPB * 64;      // 256
constexpr int NBLOCKS = 1280;          // = 5 blocks/CU exactly, all resident
constexpr int NWAVES_TOT = NBLOCKS * WPB;   // 5120
constexpr int QROWS = 8;               // rows per work unit
constexpr int UNITS = NROWS / QROWS;   // 20000 = (c, quarter) pairs

constexpr int NBUCKETS = 16;           // 1280/16 = 80 blocks per bucket
constexpr int BLOCKS_PER_BUCKET = NBLOCKS / NBUCKETS;
// d_ws layout (bytes): dsum[k] @ k*128 (f64), cnt1[k] @ 2048+k*128 (u32),
// master @ 4096 (u32). Zeroed each call by one 4104-byte memset node.

// ---- full-wave (64-lane) sum on the VALU pipe only -------------------------
template <int CTRL, int RM>
__device__ __forceinline__ float dpp_add(float x) {
    int yi = __builtin_amdgcn_update_dpp(
        __builtin_bit_cast(int, x), __builtin_bit_cast(int, x),
        CTRL, RM, 0xF, true);
    return x + __builtin_bit_cast(float, yi);
}

__device__ __forceinline__ float wave_sum_dpp(float x) {
    x = dpp_add<0xB1, 0xF>(x);   // quad_perm xor1
    x = dpp_add<0x4E, 0xF>(x);   // quad_perm xor2
    x = dpp_add<0x141, 0xF>(x);  // row_half_mirror
    x = dpp_add<0x140, 0xF>(x);  // row_mirror -> row-of-16 sums
    x = dpp_add<0x142, 0xA>(x);  // row_bcast15 (rows 1&3)
    x = dpp_add<0x143, 0xC>(x);  // row_bcast31 (rows 2&3) -> lane63 = full sum
    return __builtin_bit_cast(float,
        __builtin_amdgcn_readlane(__builtin_bit_cast(int, x), 63));
}

__global__ __launch_bounds__(THREADS) void fll_main(
    const float* __restrict__ feat,
    const float* __restrict__ emb,
    const float* __restrict__ labels,
    char* __restrict__ ws,
    float* __restrict__ out)
{
    const int lane = threadIdx.x & 63;
    const int wid  = threadIdx.x >> 6;
    const int gw   = blockIdx.x * WPB + wid;   // 0 .. 5119

    const size_t bstr = (size_t)C * D;
    float wacc = 0.0f;   // identical across lanes of the wave

    for (int u = gw; u < UNITS; u += NWAVES_TOT) {
        const int c = u >> 2;            // block's 4 waves share c -> L1 reuse
        const int q = u & 3;             // which 8-row quarter of B

        const f32x4* er = reinterpret_cast<const f32x4*>(emb + (size_t)c * D);
        const f32x4 e0 = er[lane];
        const f32x4 e1 = er[lane + 64];
        float essl = e0.x * e0.x + e0.y * e0.y + e0.z * e0.z + e0.w * e0.w
                   + e1.x * e1.x + e1.y * e1.y + e1.z * e1.z + e1.w * e1.w;
        const float ess = wave_sum_dpp(essl);

        const float* fb = feat + (size_t)(q * QROWS) * bstr + (size_t)c * D;
        const float* lb = labels + (size_t)(q * QROWS) * C + c;

        #pragma unroll 4
        for (int i = 0; i < QROWS; ++i) {
            const f32x4* fr = reinterpret_cast<const f32x4*>(fb + (size_t)i * bstr);
            const f32x4 f0 = fr[lane];
            const f32x4 f1 = fr[lane + 64];

            float dotl = f0.x * e0.x + f0.y * e0.y + f0.z * e0.z + f0.w * e0.w
                       + f1.x * e1.x + f1.y * e1.y + f1.z * e1.z + f1.w * e1.w;
            float fssl = f0.x * f0.x + f0.y * f0.y + f0.z * f0.z + f0.w * f0.w
                       + f1.x * f1.x + f1.y * f1.y + f1.z * f1.z + f1.w * f1.w;

            const float dot = wave_sum_dpp(dotl);
            const float fss = wave_sum_dpp(fssl);

            const float sim = dot / sqrtf(fss * ess);
            const float lab = lb[(size_t)i * C];    // wave-uniform
            const float S = 0.5f * (1.0f + sim) + EPS_LOG;
            const float T = 1.0f
                - ((float)(C - 1) / (float)C) * fabsf(1.0f / (float)(C - 1) + sim)
                + EPS_LOG;
            wacc += logf(lab > 0.5f ? S : T);   // labels exactly 0/1
        }
    }

    __shared__ float wsum[WPB];
    if (lane == 0) wsum[wid] = wacc;
    __syncthreads();

    if (threadIdx.x == 0) {
        const double part = (double)wsum[0] + (double)wsum[1]
                          + (double)wsum[2] + (double)wsum[3];
        const int bk = blockIdx.x & (NBUCKETS - 1);
        double*   dsum   = reinterpret_cast<double*>(ws + (size_t)bk * 128);
        unsigned* cnt1   = reinterpret_cast<unsigned*>(ws + 2048 + (size_t)bk * 128);
        unsigned* master = reinterpret_cast<unsigned*>(ws + 4096);

        atomicAdd(dsum, part);                            // memory-side f64 add
        asm volatile("s_waitcnt vmcnt(0)" ::: "memory");  // order: sum before cnt
        const unsigned o1 = atomicAdd(cnt1, 1u);
        if (o1 == (unsigned)(BLOCKS_PER_BUCKET - 1)) {    // last in bucket
            asm volatile("s_waitcnt vmcnt(0)" ::: "memory");
            const unsigned o2 = atomicAdd(master, 1u);
            if (o2 == (unsigned)(NBUCKETS - 1)) {         // globally last
                double v[NBUCKETS];
                #pragma unroll
                for (int k = 0; k < NBUCKETS; ++k)        // 16 independent reads
                    v[k] = atomicAdd(reinterpret_cast<double*>(ws + (size_t)k * 128), 0.0);
                double tot = 0.0;
                #pragma unroll
                for (int k = 0; k < NBUCKETS; ++k) tot += v[k];
                out[0] = (float)(-tot / (double)NROWS);
            }
        }
    }
}

extern "C" void kernel_launch(void* const* d_in, const int* in_sizes, int n_in,
                              void* d_out, int out_size, void* d_ws, size_t ws_size,
                              hipStream_t stream) {
    const float* feat   = (const float*)d_in[0];   // (B, C, D)
    const float* emb    = (const float*)d_in[1];   // (C, D)
    const float* labels = (const float*)d_in[2];   // (B, C)
    float* out = (float*)d_out;

    hipMemsetAsync(d_ws, 0, 4104, stream);   // zero buckets+counters (capturable)
    fll_main<<<NBLOCKS, THREADS, 0, stream>>>(feat, emb, labels,
                                              (char*)d_ws, out);
}

// Round 11
// 60.083 us; speedup vs baseline: 1.2464x; 1.2464x over previous
//
#include <hip/hip_runtime.h>
#include <math.h>

// FeatureLabelLoss: features (B,C,D) f32, embeddings (C,D) f32, labels (B,C) f32
// -> scalar f32 loss.  BW-bound on the 327.7 MB features stream.
//
// Lessons:
//  R2 (+254us), R5 (+79us), R9 (+10.7us): ANY fused single-kernel finish
//    (fences / same-line atomics / bucketed atomics+counters) loses to the
//    plain two-kernel finish (~4-6us). Fusion abandoned.
//  R6: tail/balance is NOT the limiter. R7: LDS emb tile = worse (DS traffic).
//  R8 (best, 64.15us): DPP (VALU-only) wave reductions, zero DS ops in hot
//    loop; main dispatch ~59-60us at ~5.8 TB/s (~92% of copy ceiling).
//
// R10 = R8 revert + ONE variable: nontemporal feature loads (evict-first on
// the zero-reuse stream; emb/labels keep L2 residency).

typedef float f32x4 __attribute__((ext_vector_type(4)));

constexpr int B = 32;
constexpr int C = 5000;
constexpr int D = 512;                 // 512 floats = 2 f32x4 per lane
constexpr int NROWS = B * C;           // 160000
constexpr float EPS_LOG = 1e-6f;

constexpr int WPB = 4;                 // waves per block
constexpr int THREADS = WPB * 64;      // 256
constexpr int NBLOCKS = 1280;          // = 5 blocks/CU exactly, all resident
constexpr int NWAVES_TOT = NBLOCKS * WPB;   // 5120
constexpr int QROWS = 8;               // rows per work unit
constexpr int UNITS = NROWS / QROWS;   // 20000 = (c, quarter) pairs

// ---- full-wave (64-lane) sum on the VALU pipe only -------------------------
template <int CTRL, int RM>
__device__ __forceinline__ float dpp_add(float x) {
    int yi = __builtin_amdgcn_update_dpp(
        __builtin_bit_cast(int, x), __builtin_bit_cast(int, x),
        CTRL, RM, 0xF, true);
    return x + __builtin_bit_cast(float, yi);
}

__device__ __forceinline__ float wave_sum_dpp(float x) {
    x = dpp_add<0xB1, 0xF>(x);   // quad_perm xor1
    x = dpp_add<0x4E, 0xF>(x);   // quad_perm xor2
    x = dpp_add<0x141, 0xF>(x);  // row_half_mirror
    x = dpp_add<0x140, 0xF>(x);  // row_mirror -> row-of-16 sums
    x = dpp_add<0x142, 0xA>(x);  // row_bcast15 (rows 1&3)
    x = dpp_add<0x143, 0xC>(x);  // row_bcast31 (rows 2&3) -> lane63 = full sum
    return __builtin_bit_cast(float,
        __builtin_amdgcn_readlane(__builtin_bit_cast(int, x), 63));
}

__global__ __launch_bounds__(THREADS) void fll_main(
    const float* __restrict__ feat,
    const float* __restrict__ emb,
    const float* __restrict__ labels,
    float* __restrict__ partial)
{
    const int lane = threadIdx.x & 63;
    const int wid  = threadIdx.x >> 6;
    const int gw   = blockIdx.x * WPB + wid;   // 0 .. 5119

    const size_t bstr = (size_t)C * D;
    float wacc = 0.0f;   // identical across lanes of the wave

    // units u, u+5120, u+10240, u+15360: block's 4 waves share c each round
    for (int u = gw; u < UNITS; u += NWAVES_TOT) {
        const int c = u >> 2;
        const int q = u & 3;             // which 8-row quarter of B

        const f32x4* er = reinterpret_cast<const f32x4*>(emb + (size_t)c * D);
        const f32x4 e0 = er[lane];
        const f32x4 e1 = er[lane + 64];
        float essl = e0.x * e0.x + e0.y * e0.y + e0.z * e0.z + e0.w * e0.w
                   + e1.x * e1.x + e1.y * e1.y + e1.z * e1.z + e1.w * e1.w;
        const float ess = wave_sum_dpp(essl);

        const float* fb = feat + (size_t)(q * QROWS) * bstr + (size_t)c * D;
        const float* lb = labels + (size_t)(q * QROWS) * C + c;

        #pragma unroll 4
        for (int i = 0; i < QROWS; ++i) {
            const f32x4* fr = reinterpret_cast<const f32x4*>(fb + (size_t)i * bstr);
            const f32x4 f0 = __builtin_nontemporal_load(fr + lane);
            const f32x4 f1 = __builtin_nontemporal_load(fr + lane + 64);

            float dotl = f0.x * e0.x + f0.y * e0.y + f0.z * e0.z + f0.w * e0.w
                       + f1.x * e1.x + f1.y * e1.y + f1.z * e1.z + f1.w * e1.w;
            float fssl = f0.x * f0.x + f0.y * f0.y + f0.z * f0.z + f0.w * f0.w
                       + f1.x * f1.x + f1.y * f1.y + f1.z * f1.z + f1.w * f1.w;

            const float dot = wave_sum_dpp(dotl);
            const float fss = wave_sum_dpp(fssl);

            const float sim = dot / sqrtf(fss * ess);
            const float lab = lb[(size_t)i * C];    // wave-uniform
            const float S = 0.5f * (1.0f + sim) + EPS_LOG;
            const float T = 1.0f
                - ((float)(C - 1) / (float)C) * fabsf(1.0f / (float)(C - 1) + sim)
                + EPS_LOG;
            wacc += logf(lab > 0.5f ? S : T);   // labels exactly 0/1
        }
    }

    __shared__ float wsum[WPB];
    if (lane == 0) wsum[wid] = wacc;
    __syncthreads();
    if (threadIdx.x == 0) {
        float s = 0.0f;
        #pragma unroll
        for (int w = 0; w < WPB; ++w) s += wsum[w];
        partial[blockIdx.x] = s;   // written fresh every launch
    }
}

__global__ __launch_bounds__(256) void fll_reduce(
    const float* __restrict__ partial, float* __restrict__ out)
{
    const int lane = threadIdx.x & 63;
    const int wave = threadIdx.x >> 6;
    double acc = 0.0;
    for (int i = threadIdx.x; i < NBLOCKS; i += 256) acc += (double)partial[i];

    #pragma unroll
    for (int off = 32; off > 0; off >>= 1) acc += __shfl_xor(acc, off, 64);

    __shared__ double sd[4];
    if (lane == 0) sd[wave] = acc;
    __syncthreads();
    if (threadIdx.x == 0) {
        double tot = 0.0;
        #pragma unroll
        for (int w = 0; w < 4; ++w) tot += sd[w];
        out[0] = (float)(-tot / (double)NROWS);
    }
}

extern "C" void kernel_launch(void* const* d_in, const int* in_sizes, int n_in,
                              void* d_out, int out_size, void* d_ws, size_t ws_size,
                              hipStream_t stream) {
    const float* feat   = (const float*)d_in[0];   // (B, C, D)
    const float* emb    = (const float*)d_in[1];   // (C, D)
    const float* labels = (const float*)d_in[2];   // (B, C)
    float* out = (float*)d_out;
    float* partial = (float*)d_ws;                 // NBLOCKS floats

    fll_main<<<NBLOCKS, THREADS, 0, stream>>>(feat, emb, labels, partial);
    fll_reduce<<<1, 256, 0, stream>>>(partial, out);
}